// Round 7
// baseline (447.191 us; speedup 1.0000x reference)
//
#include <hip/hip_runtime.h>
#include <hip/hip_bf16.h>

#define M_DIM 8192
#define N_DIM 11008
#define K_DIM 4096
#define NT 32                        // K-tiles of BK=128 (int8)
#define RROW ((size_t)64 * K_DIM)    // 64 rows of int8, in bytes

typedef __attribute__((ext_vector_type(4))) int i32x4;

// ---------------- per-token activation quant: n = rint(x/s), s = max(absmax,1e-5)/7 ----------------
__global__ void quant_x_kernel(const float* __restrict__ x,
                               char* __restrict__ xq, float* __restrict__ sx) {
  const int row = blockIdx.x;      // 8192
  const int t = threadIdx.x;       // 256
  const float4* xr4 = (const float4*)(x + (size_t)row * K_DIM);
  float4 v[4];
  float amax = 0.0f;
#pragma unroll
  for (int i = 0; i < 4; ++i) {
    v[i] = xr4[t + 256 * i];
    amax = fmaxf(amax, fmaxf(fmaxf(fabsf(v[i].x), fabsf(v[i].y)),
                             fmaxf(fabsf(v[i].z), fabsf(v[i].w))));
  }
#pragma unroll
  for (int off = 32; off > 0; off >>= 1)
    amax = fmaxf(amax, __shfl_xor(amax, off, 64));
  __shared__ float red[4];
  if ((t & 63) == 0) red[t >> 6] = amax;
  __syncthreads();
  amax = fmaxf(fmaxf(red[0], red[1]), fmaxf(red[2], red[3]));
  const float s = fmaxf(amax, 1e-5f) / 7.0f;   // matches reference bitwise
  if (t == 0) sx[row] = s;
  char q[16];
#pragma unroll
  for (int i = 0; i < 4; ++i) {
    q[i * 4 + 0] = (char)(int)rintf(v[i].x / s);  // RNE, exact ints in [-7,7]
    q[i * 4 + 1] = (char)(int)rintf(v[i].y / s);
    q[i * 4 + 2] = (char)(int)rintf(v[i].z / s);
    q[i * 4 + 3] = (char)(int)rintf(v[i].w / s);
  }
  *(int4*)(xq + (size_t)row * K_DIM + t * 16) = *(int4*)q;
}

// ---------------- per-output-channel weight quant: int8 / 127 ----------------
__global__ void quant_w_kernel(const float* __restrict__ w,
                               char* __restrict__ wq, float* __restrict__ sw) {
  const int row = blockIdx.x;      // 11008
  const int t = threadIdx.x;       // 256
  const float4* wr4 = (const float4*)(w + (size_t)row * K_DIM);
  float4 v[4];
  float amax = 0.0f;
#pragma unroll
  for (int i = 0; i < 4; ++i) {
    v[i] = wr4[t + 256 * i];
    amax = fmaxf(amax, fmaxf(fmaxf(fabsf(v[i].x), fabsf(v[i].y)),
                             fmaxf(fabsf(v[i].z), fabsf(v[i].w))));
  }
#pragma unroll
  for (int off = 32; off > 0; off >>= 1)
    amax = fmaxf(amax, __shfl_xor(amax, off, 64));
  __shared__ float red[4];
  if ((t & 63) == 0) red[t >> 6] = amax;
  __syncthreads();
  amax = fmaxf(fmaxf(red[0], red[1]), fmaxf(red[2], red[3]));
  const float s = fmaxf(amax, 1e-30f) / 127.0f;
  if (t == 0) sw[row] = s;
  char q[16];
#pragma unroll
  for (int i = 0; i < 4; ++i) {
    q[i * 4 + 0] = (char)(int)rintf(v[i].x / s);  // in [-127,127]
    q[i * 4 + 1] = (char)(int)rintf(v[i].y / s);
    q[i * 4 + 2] = (char)(int)rintf(v[i].z / s);
    q[i * 4 + 3] = (char)(int)rintf(v[i].w / s);
  }
  *(int4*)(wq + (size_t)row * K_DIM + t * 16) = *(int4*)q;
}

// ---------------- GEMM ----------------
// 256x256 tile, BK=128 int8, 512 thr (8 waves 2x4), ring-2 LDS 128 KiB, 1 block/CU,
// 2 waves/SIMD (waves w and w+4 share a SIMD; they differ in wm). MFMA groups of a
// tile commute, so wm=1 waves run the carried pending MFMA cluster in an EXCLUSIVE
// sched region at tile start while wm=0 waves start with ds_reads -> the SIMD's two
// waves are phase-staggered by one MFMA cluster; LDS pipe overlaps matrix pipe.
// Swizzle (verified 0 conflicts): phys = row*128 + (col ^ ((row&7)<<4)),
// staged via inverse-swizzled global source (linear gload_lds dest).
#define GL(g, d)                                                             \
  __builtin_amdgcn_global_load_lds(                                          \
      (const __attribute__((address_space(1))) void*)(g),                    \
      (__attribute__((address_space(3))) void*)(d), 16, 0, 0)

template<int KK>
__device__ __forceinline__ void read_g1(const char* paRow, const char* pbRow, int colswz,
                                        i32x4 (&a)[4], i32x4 (&b)[4]) {
  const int c = colswz ^ (KK * 64);
#pragma unroll
  for (int i = 0; i < 4; ++i) a[i] = *(const i32x4*)(paRow + i * 2048 + c);
#pragma unroll
  for (int i = 0; i < 4; ++i) b[i] = *(const i32x4*)(pbRow + i * 2048 + c);
}
template<int KK>
__device__ __forceinline__ void read_g2(const char* paRow, int colswz, i32x4 (&a)[4]) {
  const int c = colswz ^ (KK * 64);
#pragma unroll
  for (int i = 0; i < 4; ++i) a[i] = *(const i32x4*)(paRow + 8192 + i * 2048 + c);
}
template<int OFF>
__device__ __forceinline__ void mfma16(const i32x4 (&a)[4], const i32x4 (&b)[4],
                                       i32x4 (&acc)[8][4]) {
#pragma unroll
  for (int m = 0; m < 4; ++m)
#pragma unroll
    for (int n = 0; n < 4; ++n)
      acc[OFF + m][n] = __builtin_amdgcn_mfma_i32_16x16x64_i8(a[m], b[n], acc[OFF + m][n], 0, 0, 0);
}

template<bool FIRST, bool STG>
__device__ __forceinline__ void tile(const char* paRow, const char* pbRow, int colswz,
    const char* gAn, const char* gBn, char* dA, char* dB, bool stag,
    i32x4 (&acc)[8][4], i32x4 (&bP)[4], i32x4 (&a2P)[4]) {
  __syncthreads();  // tile's buffer staged & other buffer's readers done
  if constexpr (STG) {
    GL(gAn, dA);                    GL(gAn + 2 * RROW, dA + 16384);
    GL(gBn, dB);                    GL(gBn + RROW, dB + 8192);
    GL(gBn + 2 * RROW, dB + 16384); GL(gBn + 3 * RROW, dB + 24576);
    GL(gAn + RROW, dA + 8192);      GL(gAn + 3 * RROW, dA + 24576);
  }
  i32x4 a10[4], b0[4], a20[4], a11[4], b1[4], a21[4];
  if constexpr (!FIRST) {
    if (stag) {  // wm=1 waves: pending MFMA cluster EXCLUSIVE first (matrix burst
                 // covers partner wave's read phase on the same SIMD)
      __builtin_amdgcn_sched_barrier(0);
      mfma16<4>(a2P, bP, acc);
      __builtin_amdgcn_sched_barrier(0);
    }
  }
  // seg1: reads g1(k0) || (wm=0) pending MFMA
  read_g1<0>(paRow, pbRow, colswz, a10, b0);
  if constexpr (!FIRST) {
    if (!stag) mfma16<4>(a2P, bP, acc);
  }
  __builtin_amdgcn_sched_barrier(0);
  // seg2: reads g2(k0) || MFMA g1(k0)
  read_g2<0>(paRow, colswz, a20);
  mfma16<0>(a10, b0, acc);
  __builtin_amdgcn_sched_barrier(0);
  // seg3: reads g1(k1) || MFMA g2(k0)
  read_g1<1>(paRow, pbRow, colswz, a11, b1);
  mfma16<4>(a20, b0, acc);
  __builtin_amdgcn_sched_barrier(0);
  // seg4: reads g2(k1) || MFMA g1(k1); g2(k1) becomes next tile's pending
  read_g2<1>(paRow, colswz, a21);
  mfma16<0>(a11, b1, acc);
#pragma unroll
  for (int i = 0; i < 4; ++i) { bP[i] = b1[i]; a2P[i] = a21[i]; }
}

__global__ __launch_bounds__(512, 2) void gemm_kernel(
    const char* __restrict__ xq, const char* __restrict__ wq,
    const float* __restrict__ sx, const float* __restrict__ sw,
    const float* __restrict__ bias, float* __restrict__ out) {
  __shared__ char lds_c[131072];  // A: [0,64K) bufs 0/1; B: [64K,128K) bufs 0/1

  const int tid = threadIdx.x;
  const int lane = tid & 63;
  const int wave = tid >> 6;
  const int wm = wave >> 2;       // 0..1 — also the SIMD-pair stagger parity
  const int wn = wave & 3;        // 0..3
  const int lr = lane & 15;
  const bool stag = (wm == 1);

  // T1: bijective XCD swizzle (1376 = 8*172)
  const int bid = blockIdx.x;
  const int sw_id = (bid & 7) * 172 + (bid >> 3);
  const int bm = sw_id / 43, bn = sw_id % 43;
  const int m0 = bm * 256, n0 = bn * 256;

  // staging source: thread t -> row tid>>3 (0..63), phys colbyte (tid&7)*16,
  // source colbyte = phys ^ ((row&7)<<4)   (inverse swizzle)
  const int srow = tid >> 3;
  const int srccb = ((tid & 7) << 4) ^ ((srow & 7) << 4);
  const char* gA0 = xq + (size_t)(m0 + srow) * K_DIM + srccb;
  const char* gB0 = wq + (size_t)(n0 + srow) * K_DIM + srccb;
  char* dA0 = lds_c + wave * 1024;            // wave-uniform; HW adds lane*16
  char* dB0 = lds_c + 65536 + wave * 1024;

  // read-side bases
  const int aRowOff = (wm * 128 + lr) * 128;
  const int bRowOff = (wn * 64 + lr) * 128;
  const int colswz = ((lane >> 4) << 4) ^ ((lr & 7) << 4);

  i32x4 acc[8][4] = {};
  i32x4 bP[4], a2P[4];

  // prologue: stage tile 0 into buf 0 (drained by the first tile's barrier)
  GL(gA0, dA0);                    GL(gA0 + 2 * RROW, dA0 + 16384);
  GL(gB0, dB0);                    GL(gB0 + RROW, dB0 + 8192);
  GL(gB0 + 2 * RROW, dB0 + 16384); GL(gB0 + 3 * RROW, dB0 + 24576);
  GL(gA0 + RROW, dA0 + 8192);      GL(gA0 + 3 * RROW, dA0 + 24576);

  tile<true, true>(lds_c + aRowOff, lds_c + 65536 + bRowOff, colswz,
                   gA0 + 128, gB0 + 128, dA0 + 32768, dB0 + 32768, stag, acc, bP, a2P);
  for (int t = 1; t < NT - 1; ++t) {
    const int buf = t & 1;
    tile<false, true>(lds_c + buf * 32768 + aRowOff,
                      lds_c + 65536 + buf * 32768 + bRowOff, colswz,
                      gA0 + (size_t)(t + 1) * 128, gB0 + (size_t)(t + 1) * 128,
                      dA0 + (1 - buf) * 32768, dB0 + (1 - buf) * 32768, stag, acc, bP, a2P);
  }
  tile<false, false>(lds_c + ((NT - 1) & 1) * 32768 + aRowOff,
                     lds_c + 65536 + ((NT - 1) & 1) * 32768 + bRowOff, colswz,
                     nullptr, nullptr, nullptr, nullptr, stag, acc, bP, a2P);
  mfma16<4>(a2P, bP, acc);  // final pending group

  // epilogue: C/D layout col=lane&15, row=(lane>>4)*4+reg (dtype-independent, m121/m128)
  const int orow0 = m0 + wm * 128 + (lane >> 4) * 4;
  const int ocol0 = n0 + wn * 64 + lr;
  float bv[4], swv[4];
#pragma unroll
  for (int fc = 0; fc < 4; ++fc) {
    bv[fc] = bias[ocol0 + fc * 16];
    swv[fc] = sw[ocol0 + fc * 16];
  }
#pragma unroll
  for (int fr = 0; fr < 8; ++fr) {
#pragma unroll
    for (int j = 0; j < 4; ++j) {
      const int grow = orow0 + fr * 16 + j;
      const float s = sx[grow];
      float* op = out + (size_t)grow * N_DIM + ocol0;
#pragma unroll
      for (int fc = 0; fc < 4; ++fc)
        op[fc * 16] = (float)acc[fr][fc][j] * (s * swv[fc]) + bv[fc];
    }
  }
}

extern "C" void kernel_launch(void* const* d_in, const int* in_sizes, int n_in,
                              void* d_out, int out_size, void* d_ws, size_t ws_size,
                              hipStream_t stream) {
  (void)in_sizes; (void)n_in; (void)out_size; (void)ws_size;
  const float* x = (const float*)d_in[0];       // [4,2048,4096] f32
  const float* w = (const float*)d_in[1];       // [11008,4096] f32
  const float* bias = (const float*)d_in[2];    // [1,11008] f32
  float* out = (float*)d_out;                   // [8192,11008] f32

  char* ws = (char*)d_ws;
  float* sx = (float*)ws;                                   // 32 KiB
  float* sw = (float*)(ws + 32768);                         // 44 KiB
  char* xq8 = ws + 131072;                                  // 32 MiB int8
  char* wq8 = ws + 131072 + (size_t)M_DIM * K_DIM;          // 43 MiB int8

  quant_x_kernel<<<M_DIM, 256, 0, stream>>>(x, xq8, sx);
  quant_w_kernel<<<N_DIM, 256, 0, stream>>>(w, wq8, sw);
  gemm_kernel<<<dim3((M_DIM / 256) * (N_DIM / 256)), 512, 0, stream>>>(xq8, wq8, sx, sw, bias, out);
}